// Round 20
// baseline (231.508 us; speedup 1.0000x reference)
//
#include <hip/hip_runtime.h>
#include <hip/hip_bf16.h>
#include <cmath>

typedef __bf16 bf16_t;
typedef __bf16 bf16x8 __attribute__((ext_vector_type(8)));
typedef float  f32x4  __attribute__((ext_vector_type(4)));

#define AS1(p) ((__attribute__((address_space(1))) void*)(p))
#define AS3(p) ((__attribute__((address_space(3))) void*)(p))

// N=8192, H=512, TAU=0.5, EPS=1e-8
// exp(x) = exp2(x * log2e / TAU); (1/0.5)*log2e = 2.885390...
#define C_EXP2 2.8853900817779268f
#define NROWS  8192
#define HDIM   512

// ---------------------------------------------------------------- f32->bf16 (weights only)
__global__ __launch_bounds__(256) void cvt_f32_bf16(const float* __restrict__ src,
                                                    bf16_t* __restrict__ dst, int n8) {
    int i = blockIdx.x * 256 + threadIdx.x;
    if (i >= n8) return;
    const f32x4* s4 = (const f32x4*)src;
    f32x4 a = s4[2 * (size_t)i];
    f32x4 b = s4[2 * (size_t)i + 1];
    bf16x8 o;
#pragma unroll
    for (int j = 0; j < 4; ++j) { o[j] = (bf16_t)a[j]; o[4 + j] = (bf16_t)b[j]; }
    *(bf16x8*)(dst + 8 * (size_t)i) = o;
}

// ---------------------------------------------------------------- MLP GEMM (NT)
// (unchanged from R15/R17 — proven)
template <int EPI>
__global__ __launch_bounds__(256, 2)
void gemm_bt(const float* __restrict__ A0, const float* __restrict__ A1,
             const bf16_t* __restrict__ Abf,
             const bf16_t* __restrict__ B,
             const float* __restrict__ bias,
             bf16_t* __restrict__ outb, float* __restrict__ outf) {
    constexpr int K  = 512;
    constexpr int NT = 8;
    __shared__ __align__(16) char smem[65536];

    const int tid  = threadIdx.x;
    const int lane = tid & 63;
    const int wv   = tid >> 6;
    const int wm   = wv >> 1;
    const int wn   = wv & 1;

    const long ibase = (long)blockIdx.x * 128;
    const long jbase = (long)blockIdx.y * 128;

    const int r8  = lane >> 3;
    const int c16 = lane & 7;
    const long bSrc0 = (jbase + wv * 32 + r8) * (long)K + ((c16 ^ r8) << 3);

    const float* Af = nullptr;
    long aSrcF = 0, aSrcB = 0;
    if constexpr (EPI == 1) {
        Af = (blockIdx.x < 64) ? A0 : A1;
        aSrcF = (((long)(blockIdx.x & 63) * 128) + wv * 32 + r8) * (long)K + ((c16 ^ r8) << 3);
    } else {
        aSrcB = (ibase + wv * 32 + r8) * (long)K + ((c16 ^ r8) << 3);
    }

    f32x4 acc[4][4] = {};
    const int fr = lane & 15;
    const int fj = lane >> 4;
    const int crow = fj << 2;
    const int ccol = fr;

    f32x4 fa[4][2];

#pragma unroll
    for (int s = 0; s < 4; ++s) {
        const int ro = (wv * 32 + s * 8) * 128;
        if constexpr (EPI == 1) {
            const float* p = Af + aSrcF + s * 8 * K;
            fa[s][0] = *(const f32x4*)p;
            fa[s][1] = *(const f32x4*)(p + 4);
        } else {
            __builtin_amdgcn_global_load_lds(AS1(Abf + aSrcB + s * 8 * K), AS3(smem + ro), 16, 0, 0);
        }
        __builtin_amdgcn_global_load_lds(AS1(B + bSrc0 + s * 8 * K), AS3(smem + 32768 + ro), 16, 0, 0);
    }
    asm volatile("s_waitcnt vmcnt(0)" ::: "memory");
    if constexpr (EPI == 1) {
#pragma unroll
        for (int s = 0; s < 4; ++s) {
            bf16x8 o;
#pragma unroll
            for (int j = 0; j < 4; ++j) { o[j] = (bf16_t)fa[s][0][j]; o[4 + j] = (bf16_t)fa[s][1][j]; }
            *(bf16x8*)(smem + (wv * 32 + s * 8 + r8) * 128 + (c16 << 4)) = o;   // linear dest
        }
        asm volatile("s_waitcnt lgkmcnt(0)" ::: "memory");
    }
    __builtin_amdgcn_s_barrier();
    asm volatile("" ::: "memory");

#pragma unroll
    for (int t = 0; t < NT; ++t) {
        const int nb = (t + 1) & 1;
        if (t + 1 < NT) {
#pragma unroll
            for (int s = 0; s < 4; ++s) {
                const int ro = (wv * 32 + s * 8) * 128;
                if constexpr (EPI == 1) {
                    const float* p = Af + aSrcF + s * 8 * K + (t + 1) * 64;
                    fa[s][0] = *(const f32x4*)p;
                    fa[s][1] = *(const f32x4*)(p + 4);
                } else {
                    __builtin_amdgcn_global_load_lds(AS1(Abf + aSrcB + s * 8 * K + (t + 1) * 64),
                                                     AS3(smem + nb * 16384 + ro), 16, 0, 0);
                }
                __builtin_amdgcn_global_load_lds(AS1(B + bSrc0 + s * 8 * K + (t + 1) * 64),
                                                 AS3(smem + 32768 + nb * 16384 + ro), 16, 0, 0);
            }
        }
        asm volatile("" ::: "memory");
#pragma unroll
        for (int kk = 0; kk < 2; ++kk) {
            bf16x8 af[4], bfr[4];
#pragma unroll
            for (int m = 0; m < 4; ++m) {
                const int row = wm * 64 + m * 16 + fr;
                af[m] = *(const bf16x8*)(smem + (t & 1) * 16384 + row * 128 +
                                         (((kk * 4 + fj) ^ (fr & 7)) << 4));
            }
#pragma unroll
            for (int n = 0; n < 4; ++n) {
                const int row = wn * 64 + n * 16 + fr;
                bfr[n] = *(const bf16x8*)(smem + 32768 + (t & 1) * 16384 + row * 128 +
                                          (((kk * 4 + fj) ^ (fr & 7)) << 4));
            }
            __builtin_amdgcn_s_setprio(1);
#pragma unroll
            for (int m = 0; m < 4; ++m)
#pragma unroll
                for (int n = 0; n < 4; ++n)
                    acc[m][n] = __builtin_amdgcn_mfma_f32_16x16x32_bf16(af[m], bfr[n],
                                                                        acc[m][n], 0, 0, 0);
            __builtin_amdgcn_s_setprio(0);
        }
        asm volatile("" ::: "memory");
        if (t + 1 < NT) {
            asm volatile("s_waitcnt vmcnt(0)" ::: "memory");
            if constexpr (EPI == 1) {
#pragma unroll
                for (int s = 0; s < 4; ++s) {
                    bf16x8 o;
#pragma unroll
                    for (int j = 0; j < 4; ++j) { o[j] = (bf16_t)fa[s][0][j]; o[4 + j] = (bf16_t)fa[s][1][j]; }
                    *(bf16x8*)(smem + nb * 16384 + (wv * 32 + s * 8 + r8) * 128 + (c16 << 4)) = o;
                }
                asm volatile("s_waitcnt lgkmcnt(0)" ::: "memory");
            }
            __builtin_amdgcn_s_barrier();
            asm volatile("" ::: "memory");
        }
    }

#pragma unroll
    for (int m = 0; m < 4; ++m) {
        const long rowb = ibase + wm * 64 + m * 16 + crow;
#pragma unroll
        for (int n = 0; n < 4; ++n) {
            const int col = (int)jbase + wn * 64 + n * 16 + ccol;
            const float bv = bias[col];
#pragma unroll
            for (int r = 0; r < 4; ++r) {
                float v = acc[m][n][r] + bv;
                const long idx = (rowb + r) * HDIM + col;
                if constexpr (EPI == 1) {
                    v = v > 0.f ? v : expm1f(v);  // ELU(alpha=1)
                    outb[idx] = (bf16_t)v;
                } else {
                    outf[idx] = v;
                    outb[idx] = (bf16_t)v;
                }
            }
        }
    }
}

// ---------------------------------------------------------------- GEMM3 + pos
// R20: R17 base (2 blocks/CU — every sub-2-block structure regressed), with
// pos DUTY-CYCLE fix: 2 consecutive i-tiles per block (grid 2048).
// tile0 K-loop: pvA (tile0 pos, 4 chunks/step t<4, R17 cadence) PLUS pvB
// (tile1 pos mi=0,1; 2 chunks/step t<4). Step-end vmcnt(6) leaves exactly
// [pvA:4][pvB:2]; predecessors aged 1.3 steps drain nearly free.
// tile1 stage(0)->buf0 is issued at tile0's t=7 stage slot (buf0 dead since
// t=6-end barrier); the tile0 epilogue covers its latency. tile1 issues pvC
// (mi=2,3) at 2 chunks/step t<4 with vmcnt(2) ends. Combine scratch is a
// SEPARATE 2 KB shared array (no staging-buffer aliasing; LDS 66 KB -> 2/CU).
// Ledger audit (per-wave, uniform across waves): every wait count listed in
// comments at the wait site.
__global__ __launch_bounds__(256, 2)
void gemm_pos(const bf16_t* __restrict__ A, const bf16_t* __restrict__ B,
              const float* __restrict__ rn0, const float* __restrict__ rn1,
              const float* __restrict__ pos,
              float* __restrict__ pS, float* __restrict__ pP) {
    constexpr int K = 512;
    __shared__ __align__(16) char smem[65536];   // A dbuf [0,32K); B dbuf [32K,64K)
    __shared__ float scS[256], scP[256];         // epilogue combine (separate)

    const int tid  = threadIdx.x;
    const int lane = tid & 63;
    const int wv   = tid >> 6;   // 0..3
    const int wm   = wv >> 1;    // 0..1: 64-row (i) slab
    const int wn   = wv & 1;     // 0..1: 64-col (j) slab

    // 2048 blocks: xcd=bid&7 (j-panel group), idx>>3 = i-pair (slow), idx&7 = j (fast)
    const int bid = blockIdx.x;
    const int xcd = bid & 7;
    const int idx = bid >> 3;                  // 0..255
    const long ibase = (long)(idx >> 3) * 256; // tile0; tile1 = ibase+128
    const int  jt    = xcd * 8 + (idx & 7);    // 0..63
    const long jbase = (long)jt * 128;

    const int r8  = lane >> 3;
    const int c16 = lane & 7;
    const long aSrc0 = (ibase + wv * 32 + r8) * (long)K + ((c16 ^ r8) << 3);
    const long aSrc1 = aSrc0 + 128 * (long)K;
    const long bSrc0 = (jbase + wv * 32 + r8) * (long)K + ((c16 ^ r8) << 3);

    f32x4 acc[4][4] = {};
    const int fr = lane & 15;   // i within 16 (C col after swap)
    const int fj = lane >> 4;
    const int crow = fj << 2;   // j base within fragment
    const int ccol = fr;

    float r0v[4], r0w[4], r1v[16];
#pragma unroll
    for (int mi = 0; mi < 4; ++mi)
        r0v[mi] = rn0[ibase + wm * 64 + mi * 16 + ccol] * C_EXP2;
#pragma unroll
    for (int nj = 0; nj < 4; ++nj)
#pragma unroll
        for (int r = 0; r < 4; ++r)
            r1v[nj * 4 + r] = rn1[jbase + wn * 64 + nj * 16 + crow + r];

    f32x4 pvA[4][4];   // tile0 pos
    f32x4 pvB[2][4];   // tile1 pos, mi=0,1 (prefetched during tile0)
    f32x4 pvC[2][4];   // tile1 pos, mi=2,3 (issued during tile1)
    const float* p00 = pos + (size_t)(ibase + wm * 64 + ccol) * NROWS + jbase + wn * 64 + crow;
    const float* p01 = p00 + (size_t)128 * NROWS;

    auto STAGE = [&](int buf, long aSrc, int t) {
#pragma unroll
        for (int s = 0; s < 4; ++s)
            __builtin_amdgcn_global_load_lds(AS1(A + aSrc + s * 8 * K + t * 64),
                                             AS3(smem + buf * 16384 + (wv * 32 + s * 8) * 128), 16, 0, 0);
#pragma unroll
        for (int s = 0; s < 4; ++s)
            __builtin_amdgcn_global_load_lds(AS1(B + bSrc0 + s * 8 * K + t * 64),
                                             AS3(smem + 32768 + buf * 16384 + (wv * 32 + s * 8) * 128), 16, 0, 0);
    };

    // ---------------- prologue: [r-loads][S0:8] -> vmcnt(0), barrier
    STAGE(0, aSrc0, 0);
    asm volatile("s_waitcnt vmcnt(0)" ::: "memory");
    __builtin_amdgcn_s_barrier();
    asm volatile("" ::: "memory");

    // ================ tile0 K-loop =================
#pragma unroll
    for (int t = 0; t < 8; ++t) {
        if (t < 7)      STAGE((t + 1) & 1, aSrc0, t + 1);
        else            STAGE(0, aSrc1, 0);        // tile1 t=0 -> buf0 (dead since t6-end)
        asm volatile("" ::: "memory");             // pin: pos issues AFTER stage
        if (t < 4) {
#pragma unroll
            for (int nj = 0; nj < 4; ++nj)         // pvA: tile0, mi=t
                pvA[t][nj] = *(const f32x4*)(p00 + (size_t)(t * 16) * NROWS + nj * 16);
#pragma unroll
            for (int h = 0; h < 2; ++h) {          // pvB: tile1, chunks 2t,2t+1
                const int c = 2 * t + h;
                pvB[c >> 2][c & 3] = *(const f32x4*)(p01 + (size_t)((c >> 2) * 16) * NROWS + (c & 3) * 16);
            }
        }
#pragma unroll
        for (int kk = 0; kk < 2; ++kk) {
            bf16x8 af[4], bfr[4];
#pragma unroll
            for (int mi = 0; mi < 4; ++mi) {
                const int row = wm * 64 + mi * 16 + fr;
                af[mi] = *(const bf16x8*)(smem + (t & 1) * 16384 + row * 128 +
                                          (((kk * 4 + fj) ^ (fr & 7)) << 4));
            }
#pragma unroll
            for (int nj = 0; nj < 4; ++nj) {
                const int row = wn * 64 + nj * 16 + fr;
                bfr[nj] = *(const bf16x8*)(smem + 32768 + (t & 1) * 16384 + row * 128 +
                                           (((kk * 4 + fj) ^ (fr & 7)) << 4));
            }
            __builtin_amdgcn_s_setprio(1);
#pragma unroll
            for (int mi = 0; mi < 4; ++mi)
#pragma unroll
                for (int nj = 0; nj < 4; ++nj)
                    acc[mi][nj] = __builtin_amdgcn_mfma_f32_16x16x32_bf16(bfr[nj], af[mi],
                                                                          acc[mi][nj], 0, 0, 0);
            __builtin_amdgcn_s_setprio(0);
        }
        asm volatile("" ::: "memory");
        if (t < 7) {
            // t<4: [prev pvA:4,pvB:2][S:8][pvA:4][pvB:2] -> vmcnt(6) drains prev+S
            // t=4: [pvA3:4][pvB3:2][S5:8] -> vmcnt(0)
            // t=5,6: [S:8] -> vmcnt(0)
            if (t < 4) asm volatile("s_waitcnt vmcnt(6)" ::: "memory");
            else       asm volatile("s_waitcnt vmcnt(0)" ::: "memory");
            __builtin_amdgcn_s_barrier();
            asm volatile("" ::: "memory");
        }
    }

    // tile1 rn0 scales (queue: [S0_t1:8][r0w:..] — drained by vmcnt(0) below)
#pragma unroll
    for (int mi = 0; mi < 4; ++mi)
        r0w[mi] = rn0[ibase + 128 + wm * 64 + mi * 16 + ccol] * C_EXP2;

    // ---------------- tile0 epilogue (covers tile1-S0 + r0w latency)
    {
        float S[4] = {0.f, 0.f, 0.f, 0.f};
        float P[4] = {0.f, 0.f, 0.f, 0.f};
#pragma unroll
        for (int mi = 0; mi < 4; ++mi)
#pragma unroll
            for (int nj = 0; nj < 4; ++nj)
#pragma unroll
                for (int r = 0; r < 4; ++r) {
                    const float e = exp2f(acc[mi][nj][r] * r0v[mi] * r1v[nj * 4 + r]);
                    S[mi] += e;
                    P[mi] += e * pvA[mi][nj][r];
                }
#pragma unroll
        for (int mi = 0; mi < 4; ++mi) {
            S[mi] += __shfl_xor(S[mi], 16); S[mi] += __shfl_xor(S[mi], 32);
            P[mi] += __shfl_xor(P[mi], 16); P[mi] += __shfl_xor(P[mi], 32);
        }
        if (lane < 16) {
#pragma unroll
            for (int mi = 0; mi < 4; ++mi) {
                scS[wn * 128 + wm * 64 + mi * 16 + fr] = S[mi];
                scP[wn * 128 + wm * 64 + mi * 16 + fr] = P[mi];
            }
        }
        __syncthreads();
        if (tid < 128) {
            pS[(long)jt * NROWS + ibase + tid] = scS[tid] + scS[128 + tid];
            pP[(long)jt * NROWS + ibase + tid] = scP[tid] + scP[128 + tid];
        }
    }
#pragma unroll
    for (int mi = 0; mi < 4; ++mi)
#pragma unroll
        for (int nj = 0; nj < 4; ++nj)
            acc[mi][nj] = (f32x4){0.f, 0.f, 0.f, 0.f};
    // drain tile1-S0 + r0w (+float nothing; stores also drained — uniform across waves)
    asm volatile("s_waitcnt vmcnt(0)" ::: "memory");
    __builtin_amdgcn_s_barrier();
    asm volatile("" ::: "memory");

    // ================ tile1 K-loop =================
#pragma unroll
    for (int t = 0; t < 8; ++t) {
        if (t < 7) STAGE((t + 1) & 1, aSrc1, t + 1);
        asm volatile("" ::: "memory");
        if (t < 4) {
#pragma unroll
            for (int h = 0; h < 2; ++h) {          // pvC: tile1 mi=2,3; chunks 2t,2t+1
                const int c = 2 * t + h;
                pvC[c >> 2][c & 3] = *(const f32x4*)(p01 + (size_t)((2 + (c >> 2)) * 16) * NROWS + (c & 3) * 16);
            }
        }
#pragma unroll
        for (int kk = 0; kk < 2; ++kk) {
            bf16x8 af[4], bfr[4];
#pragma unroll
            for (int mi = 0; mi < 4; ++mi) {
                const int row = wm * 64 + mi * 16 + fr;
                af[mi] = *(const bf16x8*)(smem + (t & 1) * 16384 + row * 128 +
                                          (((kk * 4 + fj) ^ (fr & 7)) << 4));
            }
#pragma unroll
            for (int nj = 0; nj < 4; ++nj) {
                const int row = wn * 64 + nj * 16 + fr;
                bfr[nj] = *(const bf16x8*)(smem + 32768 + (t & 1) * 16384 + row * 128 +
                                           (((kk * 4 + fj) ^ (fr & 7)) << 4));
            }
            __builtin_amdgcn_s_setprio(1);
#pragma unroll
            for (int mi = 0; mi < 4; ++mi)
#pragma unroll
                for (int nj = 0; nj < 4; ++nj)
                    acc[mi][nj] = __builtin_amdgcn_mfma_f32_16x16x32_bf16(bfr[nj], af[mi],
                                                                          acc[mi][nj], 0, 0, 0);
            __builtin_amdgcn_s_setprio(0);
        }
        asm volatile("" ::: "memory");
        if (t < 7) {
            // t<4: [prev pvC:2][S:8][pvC:2] -> vmcnt(2); t>=4: [S:8] -> vmcnt(0)
            if (t < 4) asm volatile("s_waitcnt vmcnt(2)" ::: "memory");
            else       asm volatile("s_waitcnt vmcnt(0)" ::: "memory");
            __builtin_amdgcn_s_barrier();
            asm volatile("" ::: "memory");
        }
    }

    // ---------------- tile1 epilogue (pv = pvB for mi 0,1; pvC for mi 2,3)
    {
        float S[4] = {0.f, 0.f, 0.f, 0.f};
        float P[4] = {0.f, 0.f, 0.f, 0.f};
#pragma unroll
        for (int mi = 0; mi < 4; ++mi)
#pragma unroll
            for (int nj = 0; nj < 4; ++nj) {
                const f32x4 pvv = (mi < 2) ? pvB[mi][nj] : pvC[mi - 2][nj];
#pragma unroll
                for (int r = 0; r < 4; ++r) {
                    const float e = exp2f(acc[mi][nj][r] * r0w[mi] * r1v[nj * 4 + r]);
                    S[mi] += e;
                    P[mi] += e * pvv[r];
                }
            }
#pragma unroll
        for (int mi = 0; mi < 4; ++mi) {
            S[mi] += __shfl_xor(S[mi], 16); S[mi] += __shfl_xor(S[mi], 32);
            P[mi] += __shfl_xor(P[mi], 16); P[mi] += __shfl_xor(P[mi], 32);
        }
        __syncthreads();   // scS/scP reuse: tile0 readers done (stores issued)
        if (lane < 16) {
#pragma unroll
            for (int mi = 0; mi < 4; ++mi) {
                scS[wn * 128 + wm * 64 + mi * 16 + fr] = S[mi];
                scP[wn * 128 + wm * 64 + mi * 16 + fr] = P[mi];
            }
        }
        __syncthreads();
        if (tid < 128) {
            pS[(long)jt * NROWS + ibase + 128 + tid] = scS[tid] + scS[128 + tid];
            pP[(long)jt * NROWS + ibase + 128 + tid] = scP[tid] + scP[128 + tid];
        }
    }
}

// ---------------------------------------------------------------- row norms
__global__ __launch_bounds__(256) void rownorm(const bf16_t* __restrict__ Z,
                                               float* __restrict__ rn) {
    const int row  = blockIdx.x * 4 + (threadIdx.x >> 6);
    const int lane = threadIdx.x & 63;
    bf16x8 v = *(const bf16x8*)&Z[(size_t)row * HDIM + lane * 8];
    float s = 0.f;
#pragma unroll
    for (int j = 0; j < 8; ++j) { float f = (float)v[j]; s += f * f; }
#pragma unroll
    for (int off = 32; off > 0; off >>= 1) s += __shfl_xor(s, off);
    if (lane == 0) rn[row] = rsqrtf(s);
}

// ---------------------------------------------------------------- reductions
__global__ __launch_bounds__(256) void reduce_rows(const float* __restrict__ pS,
                                                   const float* __restrict__ pP,
                                                   float* __restrict__ bsum) {
    const int i = blockIdx.x * 256 + threadIdx.x;  // row 0..8191
    float S = 0.f, P = 0.f;
    for (int jb = 0; jb < 64; ++jb) {
        S += pS[jb * NROWS + i];
        P += pP[jb * NROWS + i];
    }
    float t = logf(P / (S + 1e-8f) + 1e-8f);
#pragma unroll
    for (int off = 32; off > 0; off >>= 1) t += __shfl_xor(t, off);
    __shared__ float red[4];
    if ((threadIdx.x & 63) == 0) red[threadIdx.x >> 6] = t;
    __syncthreads();
    if (threadIdx.x == 0) bsum[blockIdx.x] = red[0] + red[1] + red[2] + red[3];
}

__global__ void finalize(const float* __restrict__ bsum, float* __restrict__ loss) {
    float t = (threadIdx.x < 32) ? bsum[threadIdx.x] : 0.f;
#pragma unroll
    for (int off = 32; off > 0; off >>= 1) t += __shfl_xor(t, off);
    if (threadIdx.x == 0) *loss = -(t * (1.0f / 8192.0f));
}

// ---------------------------------------------------------------- launch
extern "C" void kernel_launch(void* const* d_in, const int* in_sizes, int n_in,
                              void* d_out, int out_size, void* d_ws, size_t ws_size,
                              hipStream_t stream) {
    const float* embd0 = (const float*)d_in[0];
    const float* embd1 = (const float*)d_in[1];
    const float* pos   = (const float*)d_in[2];
    const float* W1    = (const float*)d_in[3];
    const float* b1    = (const float*)d_in[4];
    const float* W2    = (const float*)d_in[5];
    const float* b2    = (const float*)d_in[6];
    float* out = (float*)d_out;  // [z0 | z1 | loss]

    char* ws = (char*)d_ws;
    bf16_t* Hb   = (bf16_t*)(ws);               // 16 MB  [16384][512]
    bf16_t* Zb   = (bf16_t*)(ws + 16777216);    // 16 MB
    bf16_t* W1b  = (bf16_t*)(ws + 33554432);    // 512 KB
    bf16_t* W2b  = (bf16_t*)(ws + 34078720);    // 512 KB
    float*  rn   = (float*)(ws + 34603008);     // 64 KB (rn0|rn1)
    float*  pS   = (float*)(ws + 34668544);     // 2 MB [64][8192]
    float*  pP   = (float*)(ws + 36765696);     // 2 MB
    float*  bsum = (float*)(ws + 38862848);     // 128 B

    cvt_f32_bf16<<<128, 256, 0, stream>>>(W1, W1b, 32768);
    cvt_f32_bf16<<<128, 256, 0, stream>>>(W2, W2b, 32768);

    // H = ELU(embd @ W1^T + b1), embd f32 converted in-kernel
    gemm_bt<1><<<dim3(128, 4), 256, 0, stream>>>(embd0, embd1, nullptr, W1b, b1, Hb, nullptr);
    // Z = H @ W2^T + b2 -> f32 d_out + bf16 Zb
    gemm_bt<2><<<dim3(128, 4), 256, 0, stream>>>(nullptr, nullptr, Hb, W2b, b2, Zb, out);
    rownorm<<<4096, 256, 0, stream>>>(Zb, rn);
    gemm_pos<<<2048, 256, 0, stream>>>(Zb, Zb + 4194304, rn, rn + NROWS, pos, pS, pP);
    reduce_rows<<<32, 256, 0, stream>>>(pS, pP, bsum);
    finalize<<<1, 64, 0, stream>>>(bsum, out + 8388608);
}

// Round 21
// 172.669 us; speedup vs baseline: 1.3408x; 1.3408x over previous
//
#include <hip/hip_runtime.h>
#include <hip/hip_bf16.h>
#include <cmath>

typedef __bf16 bf16_t;
typedef __bf16 bf16x8 __attribute__((ext_vector_type(8)));
typedef float  f32x4  __attribute__((ext_vector_type(4)));

#define AS1(p) ((__attribute__((address_space(1))) void*)(p))
#define AS3(p) ((__attribute__((address_space(3))) void*)(p))

// N=8192, H=512, TAU=0.5, EPS=1e-8
// exp(x) = exp2(x * log2e / TAU); (1/0.5)*log2e = 2.885390...
#define C_EXP2 2.8853900817779268f
#define NROWS  8192
#define HDIM   512

// ---------------------------------------------------------------- f32->bf16 (weights only)
__global__ __launch_bounds__(256) void cvt_f32_bf16(const float* __restrict__ src,
                                                    bf16_t* __restrict__ dst, int n8) {
    int i = blockIdx.x * 256 + threadIdx.x;
    if (i >= n8) return;
    const f32x4* s4 = (const f32x4*)src;
    f32x4 a = s4[2 * (size_t)i];
    f32x4 b = s4[2 * (size_t)i + 1];
    bf16x8 o;
#pragma unroll
    for (int j = 0; j < 4; ++j) { o[j] = (bf16_t)a[j]; o[4 + j] = (bf16_t)b[j]; }
    *(bf16x8*)(dst + 8 * (size_t)i) = o;
}

// ---------------------------------------------------------------- MLP GEMM (NT)
// 128x128 tile, BK=64, NT=8, 2-deep dbuf (proven R8/R12 structure).
// EPI=1: A = embd0/embd1 F32, fused convert (swizzled source + LINEAR LDS
//        dest, rule #21); bias+ELU -> bf16 out.
// EPI=2: A = Hb bf16 via global_load_lds; bias -> f32 (d_out) + bf16 copy.
template <int EPI>
__global__ __launch_bounds__(256, 2)
void gemm_bt(const float* __restrict__ A0, const float* __restrict__ A1,
             const bf16_t* __restrict__ Abf,
             const bf16_t* __restrict__ B,
             const float* __restrict__ bias,
             bf16_t* __restrict__ outb, float* __restrict__ outf) {
    constexpr int K  = 512;
    constexpr int NT = 8;
    __shared__ __align__(16) char smem[65536];

    const int tid  = threadIdx.x;
    const int lane = tid & 63;
    const int wv   = tid >> 6;
    const int wm   = wv >> 1;
    const int wn   = wv & 1;

    const long ibase = (long)blockIdx.x * 128;
    const long jbase = (long)blockIdx.y * 128;

    const int r8  = lane >> 3;
    const int c16 = lane & 7;
    const long bSrc0 = (jbase + wv * 32 + r8) * (long)K + ((c16 ^ r8) << 3);

    const float* Af = nullptr;
    long aSrcF = 0, aSrcB = 0;
    if constexpr (EPI == 1) {
        Af = (blockIdx.x < 64) ? A0 : A1;
        aSrcF = (((long)(blockIdx.x & 63) * 128) + wv * 32 + r8) * (long)K + ((c16 ^ r8) << 3);
    } else {
        aSrcB = (ibase + wv * 32 + r8) * (long)K + ((c16 ^ r8) << 3);
    }

    f32x4 acc[4][4] = {};
    const int fr = lane & 15;
    const int fj = lane >> 4;
    const int crow = fj << 2;
    const int ccol = fr;

    f32x4 fa[4][2];

#pragma unroll
    for (int s = 0; s < 4; ++s) {
        const int ro = (wv * 32 + s * 8) * 128;
        if constexpr (EPI == 1) {
            const float* p = Af + aSrcF + s * 8 * K;
            fa[s][0] = *(const f32x4*)p;
            fa[s][1] = *(const f32x4*)(p + 4);
        } else {
            __builtin_amdgcn_global_load_lds(AS1(Abf + aSrcB + s * 8 * K), AS3(smem + ro), 16, 0, 0);
        }
        __builtin_amdgcn_global_load_lds(AS1(B + bSrc0 + s * 8 * K), AS3(smem + 32768 + ro), 16, 0, 0);
    }
    asm volatile("s_waitcnt vmcnt(0)" ::: "memory");
    if constexpr (EPI == 1) {
#pragma unroll
        for (int s = 0; s < 4; ++s) {
            bf16x8 o;
#pragma unroll
            for (int j = 0; j < 4; ++j) { o[j] = (bf16_t)fa[s][0][j]; o[4 + j] = (bf16_t)fa[s][1][j]; }
            *(bf16x8*)(smem + (wv * 32 + s * 8 + r8) * 128 + (c16 << 4)) = o;   // linear dest
        }
        asm volatile("s_waitcnt lgkmcnt(0)" ::: "memory");
    }
    __builtin_amdgcn_s_barrier();
    asm volatile("" ::: "memory");

#pragma unroll
    for (int t = 0; t < NT; ++t) {
        const int nb = (t + 1) & 1;
        if (t + 1 < NT) {
#pragma unroll
            for (int s = 0; s < 4; ++s) {
                const int ro = (wv * 32 + s * 8) * 128;
                if constexpr (EPI == 1) {
                    const float* p = Af + aSrcF + s * 8 * K + (t + 1) * 64;
                    fa[s][0] = *(const f32x4*)p;
                    fa[s][1] = *(const f32x4*)(p + 4);
                } else {
                    __builtin_amdgcn_global_load_lds(AS1(Abf + aSrcB + s * 8 * K + (t + 1) * 64),
                                                     AS3(smem + nb * 16384 + ro), 16, 0, 0);
                }
                __builtin_amdgcn_global_load_lds(AS1(B + bSrc0 + s * 8 * K + (t + 1) * 64),
                                                 AS3(smem + 32768 + nb * 16384 + ro), 16, 0, 0);
            }
        }
        asm volatile("" ::: "memory");
#pragma unroll
        for (int kk = 0; kk < 2; ++kk) {
            bf16x8 af[4], bfr[4];
#pragma unroll
            for (int m = 0; m < 4; ++m) {
                const int row = wm * 64 + m * 16 + fr;
                af[m] = *(const bf16x8*)(smem + (t & 1) * 16384 + row * 128 +
                                         (((kk * 4 + fj) ^ (fr & 7)) << 4));
            }
#pragma unroll
            for (int n = 0; n < 4; ++n) {
                const int row = wn * 64 + n * 16 + fr;
                bfr[n] = *(const bf16x8*)(smem + 32768 + (t & 1) * 16384 + row * 128 +
                                          (((kk * 4 + fj) ^ (fr & 7)) << 4));
            }
            __builtin_amdgcn_s_setprio(1);
#pragma unroll
            for (int m = 0; m < 4; ++m)
#pragma unroll
                for (int n = 0; n < 4; ++n)
                    acc[m][n] = __builtin_amdgcn_mfma_f32_16x16x32_bf16(af[m], bfr[n],
                                                                        acc[m][n], 0, 0, 0);
            __builtin_amdgcn_s_setprio(0);
        }
        asm volatile("" ::: "memory");
        if (t + 1 < NT) {
            asm volatile("s_waitcnt vmcnt(0)" ::: "memory");
            if constexpr (EPI == 1) {
#pragma unroll
                for (int s = 0; s < 4; ++s) {
                    bf16x8 o;
#pragma unroll
                    for (int j = 0; j < 4; ++j) { o[j] = (bf16_t)fa[s][0][j]; o[4 + j] = (bf16_t)fa[s][1][j]; }
                    *(bf16x8*)(smem + nb * 16384 + (wv * 32 + s * 8 + r8) * 128 + (c16 << 4)) = o;
                }
                asm volatile("s_waitcnt lgkmcnt(0)" ::: "memory");
            }
            __builtin_amdgcn_s_barrier();
            asm volatile("" ::: "memory");
        }
    }

#pragma unroll
    for (int m = 0; m < 4; ++m) {
        const long rowb = ibase + wm * 64 + m * 16 + crow;
#pragma unroll
        for (int n = 0; n < 4; ++n) {
            const int col = (int)jbase + wn * 64 + n * 16 + ccol;
            const float bv = bias[col];
#pragma unroll
            for (int r = 0; r < 4; ++r) {
                float v = acc[m][n][r] + bv;
                const long idx = (rowb + r) * HDIM + col;
                if constexpr (EPI == 1) {
                    v = v > 0.f ? v : expm1f(v);  // ELU(alpha=1)
                    outb[idx] = (bf16_t)v;
                } else {
                    outf[idx] = v;
                    outb[idx] = (bf16_t)v;
                }
            }
        }
    }
}

// ---------------------------------------------------------------- GEMM3 + pos
// R21 = R17 VERBATIM (measured optimum 172.9 us). R16/R18/R19/R20 all
// regressed: pos-in-registers beyond pv[4][4] spills (R16/R20, WRITE_SIZE
// blowup); pos-in-LDS or persistence drops to 1 block/CU and exposes all
// latency (R19/R16); cadence variants are neutral (R18). The {VGPR, LDS,
// occupancy} triangle is closed — this is the practical plateau of the
// 128x128 / 2-block-per-CU decomposition.
// Structure: j-fast/i-slow XCD order; swapped MFMA (D col=lane&15 -> i,
// D reg -> j) so pos loads land in consumed layout; pos front-loaded
// 4 chunks/step t=0..3 with vmcnt(4) ends; t=4..6 stage-only vmcnt(0).
__global__ __launch_bounds__(256, 2)
void gemm_pos(const bf16_t* __restrict__ A, const bf16_t* __restrict__ B,
              const float* __restrict__ rn0, const float* __restrict__ rn1,
              const float* __restrict__ pos,
              float* __restrict__ pS, float* __restrict__ pP) {
    constexpr int K = 512;
    // As dbuf: [0,32K); Bs dbuf: [32K,64K)
    __shared__ __align__(16) char smem[65536];

    const int tid  = threadIdx.x;
    const int lane = tid & 63;
    const int wv   = tid >> 6;   // 0..3
    const int wm   = wv >> 1;    // 0..1: 64-row (i) slab
    const int wn   = wv & 1;     // 0..1: 64-col (j) slab

    // bijective XCD swizzle, j-fast/i-slow within XCD (4096 blocks % 8 == 0)
    const int flat = blockIdx.x;
    const int xcd  = flat & 7;
    const int idx  = flat >> 3;               // 0..511
    const long ibase = (long)(idx >> 3) * 128;
    const int  jt    = xcd * 8 + (idx & 7);   // 0..63
    const long jbase = (long)jt * 128;

    const int r8  = lane >> 3;
    const int c16 = lane & 7;
    const long aSrc0 = (ibase + wv * 32 + r8) * (long)K + ((c16 ^ r8) << 3);
    const long bSrc0 = (jbase + wv * 32 + r8) * (long)K + ((c16 ^ r8) << 3);

    f32x4 acc[4][4] = {};
    const int fr = lane & 15;   // i within 16 (C col after swap); frag row
    const int fj = lane >> 4;   // k-octet group; j-quad selector in C
    const int crow = fj << 2;   // j base within fragment
    const int ccol = fr;

    // scales (issued before staging; drained by prologue vmcnt(0))
    float r0v[4], r1v[16];
#pragma unroll
    for (int mi = 0; mi < 4; ++mi)
        r0v[mi] = rn0[ibase + wm * 64 + mi * 16 + ccol] * C_EXP2;
#pragma unroll
    for (int nj = 0; nj < 4; ++nj)
#pragma unroll
        for (int r = 0; r < 4; ++r)
            r1v[nj * 4 + r] = rn1[jbase + wn * 64 + nj * 16 + crow + r];

    f32x4 pv[4][4];  // pos fragments: pv[mi][nj] = pos[i][j..j+3]
    const float* p00 = pos + (size_t)(ibase + wm * 64 + ccol) * NROWS + jbase + wn * 64 + crow;

    // staging: A,B each 128x64 bf16 = 16 KB/buf; 4 instr/thread each
    auto STAGE = [&](int buf, int t) {
#pragma unroll
        for (int s = 0; s < 4; ++s)
            __builtin_amdgcn_global_load_lds(AS1(A + aSrc0 + s * 8 * K + t * 64),
                                             AS3(smem + buf * 16384 + (wv * 32 + s * 8) * 128), 16, 0, 0);
#pragma unroll
        for (int s = 0; s < 4; ++s)
            __builtin_amdgcn_global_load_lds(AS1(B + bSrc0 + s * 8 * K + t * 64),
                                             AS3(smem + 32768 + buf * 16384 + (wv * 32 + s * 8) * 128), 16, 0, 0);
    };

    // ---------------- prologue: stage(0), full drain, barrier
    STAGE(0, 0);
    asm volatile("s_waitcnt vmcnt(0)" ::: "memory");
    __builtin_amdgcn_s_barrier();
    asm volatile("" ::: "memory");

    // ---------------- pipelined K-loop (fully unrolled)
#pragma unroll
    for (int t = 0; t < 8; ++t) {
        if (t + 1 < 8) STAGE((t + 1) & 1, t + 1);
        asm volatile("" ::: "memory");  // pin: pv issues AFTER stage
        if (t < 4) {
            // front-loaded pos: row group mi=t, all 4 nj chunks
#pragma unroll
            for (int nj = 0; nj < 4; ++nj)
                pv[t][nj] = *(const f32x4*)(p00 + (size_t)(t * 16) * NROWS + nj * 16);
        }
        // compute on buf t&1: 2 k-halves x (4 A-frag x 4 B-frag) = 32 MFMA
#pragma unroll
        for (int kk = 0; kk < 2; ++kk) {
            bf16x8 af[4], bfr[4];
#pragma unroll
            for (int mi = 0; mi < 4; ++mi) {
                const int row = wm * 64 + mi * 16 + fr;
                af[mi] = *(const bf16x8*)(smem + (t & 1) * 16384 + row * 128 +
                                          (((kk * 4 + fj) ^ (fr & 7)) << 4));
            }
#pragma unroll
            for (int nj = 0; nj < 4; ++nj) {
                const int row = wn * 64 + nj * 16 + fr;
                bfr[nj] = *(const bf16x8*)(smem + 32768 + (t & 1) * 16384 + row * 128 +
                                           (((kk * 4 + fj) ^ (fr & 7)) << 4));
            }
            __builtin_amdgcn_s_setprio(1);
#pragma unroll
            for (int mi = 0; mi < 4; ++mi)
#pragma unroll
                for (int nj = 0; nj < 4; ++nj)
                    acc[mi][nj] = __builtin_amdgcn_mfma_f32_16x16x32_bf16(bfr[nj], af[mi],
                                                                          acc[mi][nj], 0, 0, 0);
            __builtin_amdgcn_s_setprio(0);
        }
        asm volatile("" ::: "memory");
        if (t + 1 < 8) {
            if (t < 4) asm volatile("s_waitcnt vmcnt(4)" ::: "memory");  // drain stage (+old pv), float new pv
            else       asm volatile("s_waitcnt vmcnt(0)" ::: "memory");  // pos-free steps: stage-only queue
            __builtin_amdgcn_s_barrier();
            asm volatile("" ::: "memory");
        }
    }

    // ---------------- epilogue: pure-register e; shfl over fj; LDS wn-combine
    float S[4] = {0.f, 0.f, 0.f, 0.f};
    float P[4] = {0.f, 0.f, 0.f, 0.f};
#pragma unroll
    for (int mi = 0; mi < 4; ++mi)
#pragma unroll
        for (int nj = 0; nj < 4; ++nj)
#pragma unroll
            for (int r = 0; r < 4; ++r) {
                const float e = exp2f(acc[mi][nj][r] * r0v[mi] * r1v[nj * 4 + r]);
                S[mi] += e;
                P[mi] += e * pv[mi][nj][r];
            }
#pragma unroll
    for (int mi = 0; mi < 4; ++mi) {   // reduce the 4 fj groups (same i)
        S[mi] += __shfl_xor(S[mi], 16); S[mi] += __shfl_xor(S[mi], 32);
        P[mi] += __shfl_xor(P[mi], 16); P[mi] += __shfl_xor(P[mi], 32);
    }
    // cross-wn combine: 2 KB scratch overlays As-buf0 ([0,16K)); step-7 reads
    // only buf1 regions -> no race.
    float* sc = (float*)smem;          // [S: wn x 128 | P: wn x 128]
    if (lane < 16) {
#pragma unroll
        for (int mi = 0; mi < 4; ++mi) {
            sc[wn * 128 + wm * 64 + mi * 16 + fr] = S[mi];
            sc[256 + wn * 128 + wm * 64 + mi * 16 + fr] = P[mi];
        }
    }
    __syncthreads();
    if (tid < 128) {
        pS[(long)jt * NROWS + ibase + tid] = sc[tid] + sc[128 + tid];
        pP[(long)jt * NROWS + ibase + tid] = sc[256 + tid] + sc[384 + tid];
    }
}

// ---------------------------------------------------------------- row norms
__global__ __launch_bounds__(256) void rownorm(const bf16_t* __restrict__ Z,
                                               float* __restrict__ rn) {
    const int row  = blockIdx.x * 4 + (threadIdx.x >> 6);
    const int lane = threadIdx.x & 63;
    bf16x8 v = *(const bf16x8*)&Z[(size_t)row * HDIM + lane * 8];
    float s = 0.f;
#pragma unroll
    for (int j = 0; j < 8; ++j) { float f = (float)v[j]; s += f * f; }
#pragma unroll
    for (int off = 32; off > 0; off >>= 1) s += __shfl_xor(s, off);
    if (lane == 0) rn[row] = rsqrtf(s);
}

// ---------------------------------------------------------------- reductions
__global__ __launch_bounds__(256) void reduce_rows(const float* __restrict__ pS,
                                                   const float* __restrict__ pP,
                                                   float* __restrict__ bsum) {
    const int i = blockIdx.x * 256 + threadIdx.x;  // row 0..8191
    float S = 0.f, P = 0.f;
    for (int jb = 0; jb < 64; ++jb) {
        S += pS[jb * NROWS + i];
        P += pP[jb * NROWS + i];
    }
    float t = logf(P / (S + 1e-8f) + 1e-8f);
#pragma unroll
    for (int off = 32; off > 0; off >>= 1) t += __shfl_xor(t, off);
    __shared__ float red[4];
    if ((threadIdx.x & 63) == 0) red[threadIdx.x >> 6] = t;
    __syncthreads();
    if (threadIdx.x == 0) bsum[blockIdx.x] = red[0] + red[1] + red[2] + red[3];
}

__global__ void finalize(const float* __restrict__ bsum, float* __restrict__ loss) {
    float t = (threadIdx.x < 32) ? bsum[threadIdx.x] : 0.f;
#pragma unroll
    for (int off = 32; off > 0; off >>= 1) t += __shfl_xor(t, off);
    if (threadIdx.x == 0) *loss = -(t * (1.0f / 8192.0f));
}

// ---------------------------------------------------------------- launch
extern "C" void kernel_launch(void* const* d_in, const int* in_sizes, int n_in,
                              void* d_out, int out_size, void* d_ws, size_t ws_size,
                              hipStream_t stream) {
    const float* embd0 = (const float*)d_in[0];
    const float* embd1 = (const float*)d_in[1];
    const float* pos   = (const float*)d_in[2];
    const float* W1    = (const float*)d_in[3];
    const float* b1    = (const float*)d_in[4];
    const float* W2    = (const float*)d_in[5];
    const float* b2    = (const float*)d_in[6];
    float* out = (float*)d_out;  // [z0 | z1 | loss]

    char* ws = (char*)d_ws;
    bf16_t* Hb   = (bf16_t*)(ws);               // 16 MB  [16384][512]
    bf16_t* Zb   = (bf16_t*)(ws + 16777216);    // 16 MB
    bf16_t* W1b  = (bf16_t*)(ws + 33554432);    // 512 KB
    bf16_t* W2b  = (bf16_t*)(ws + 34078720);    // 512 KB
    float*  rn   = (float*)(ws + 34603008);     // 64 KB (rn0|rn1)
    float*  pS   = (float*)(ws + 34668544);     // 2 MB [64][8192]
    float*  pP   = (float*)(ws + 36765696);     // 2 MB
    float*  bsum = (float*)(ws + 38862848);     // 128 B

    cvt_f32_bf16<<<128, 256, 0, stream>>>(W1, W1b, 32768);
    cvt_f32_bf16<<<128, 256, 0, stream>>>(W2, W2b, 32768);

    // H = ELU(embd @ W1^T + b1), embd f32 converted in-kernel
    gemm_bt<1><<<dim3(128, 4), 256, 0, stream>>>(embd0, embd1, nullptr, W1b, b1, Hb, nullptr);
    // Z = H @ W2^T + b2 -> f32 d_out + bf16 Zb
    gemm_bt<2><<<dim3(128, 4), 256, 0, stream>>>(nullptr, nullptr, Hb, W2b, b2, Zb, out);
    rownorm<<<4096, 256, 0, stream>>>(Zb, rn);
    gemm_pos<<<4096, 256, 0, stream>>>(Zb, Zb + 4194304, rn, rn + NROWS, pos, pS, pP);
    reduce_rows<<<32, 256, 0, stream>>>(pS, pP, bsum);
    finalize<<<1, 64, 0, stream>>>(bsum, out + 8388608);
}